// Round 1
// 244.316 us; speedup vs baseline: 1.0381x; 1.0381x over previous
//
#include <hip/hip_runtime.h>
#include <math.h>

#define NEG_INF -1000000000.0f

// Problem constants
#define WL_  20
#define D1_  300
#define D2_  300
#define OUT_ 300
#define BS_  4096                 // (b,s) pairs
#define PPB  4                    // pairs per block
#define NBLK (BS_ / PPB)          // 1024 blocks
#define BM   80                   // rows per block = 5 M-tiles
#define KS   10                   // k-steps of 32 (K = 320)
#define FR   512                  // shorts per fragment slab [64 lanes][8]

typedef __attribute__((ext_vector_type(8))) short bf16x8;
typedef __attribute__((ext_vector_type(8))) short short8v;
typedef __attribute__((ext_vector_type(4))) float f32x4;
typedef __attribute__((ext_vector_type(4))) unsigned int uint4v;

// Fallback storage (only used if workspace too small). Preferred path: d_ws.
__device__ short g_Bpk[KS * 20 * FR];
__device__ short g_Vpk[256 * KS * FR];
__device__ short g_Wvpk[KS * 20 * FR];
__device__ float g_vlin[(size_t)BS_ * 320];

__device__ inline short f2bf(float f) {
    unsigned u = __float_as_uint(f);
    u += 0x7FFFu + ((u >> 16) & 1u);   // RNE
    return (short)(u >> 16);
}
__device__ inline float bf2f(short s) {
    return __uint_as_float(((unsigned)(unsigned short)s) << 16);
}

// round-half-up fp32->bf16 pack of 8 floats -> 16B fragment store
__device__ inline void pack_store(short* Am, int s, int lane, float4 fa, float4 fb) {
    unsigned u0 = __float_as_uint(fa.x) + 0x8000u;
    unsigned u1 = __float_as_uint(fa.y) + 0x8000u;
    unsigned u2 = __float_as_uint(fa.z) + 0x8000u;
    unsigned u3 = __float_as_uint(fa.w) + 0x8000u;
    unsigned u4 = __float_as_uint(fb.x) + 0x8000u;
    unsigned u5 = __float_as_uint(fb.y) + 0x8000u;
    unsigned u6 = __float_as_uint(fb.z) + 0x8000u;
    unsigned u7 = __float_as_uint(fb.w) + 0x8000u;
    uint4v w;
    w.x = __builtin_amdgcn_perm(u1, u0, 0x07060302u);
    w.y = __builtin_amdgcn_perm(u3, u2, 0x07060302u);
    w.z = __builtin_amdgcn_perm(u5, u4, 0x07060302u);
    w.w = __builtin_amdgcn_perm(u7, u6, 0x07060302u);
    *(uint4v*)(Am + ((size_t)s * 64 + lane) * 8) = w;
}

#define GV (256 * KS * 64)        // 163,840 vec fragment-groups
#define GB (KS * 20 * 64)         // 12,800  W fragment-groups
#define GT (GV + GB + GB)

__global__ __launch_bounds__(256) void prep_small(
    const float* __restrict__ vec, const float* __restrict__ W,
    const float* __restrict__ bias,
    short* Bpk, short* Vpk, short* Wvpk)
{
    if (!Bpk) { Bpk = g_Bpk; Vpk = g_Vpk; Wvpk = g_Wvpk; }
    const int id = blockIdx.x * 256 + threadIdx.x;
    if (id >= GT) return;
    short8v o8 = {0, 0, 0, 0, 0, 0, 0, 0};
    if (id < GV) {
        const int lane = id & 63, g = id >> 6;
        const int q = lane >> 4, l15 = lane & 15;
        const int ks = g % KS, mtile = g / KS;
        const int row = mtile * 16 + l15;          // pair index < 4096
        const int k0 = ks * 32 + q * 8;
        const float* s = vec + (size_t)row * D2_ + k0;
        #pragma unroll
        for (int e = 0; e < 8; ++e) {
            const int k = k0 + e;
            if (k < D2_) o8[e] = f2bf(s[e]);
            else if (k == 319) o8[e] = (short)0x3F80;   // 1.0 (bias column)
        }
        *(short8v*)(Vpk + (size_t)id * 8) = o8;
    } else if (id < GV + GB) {
        const int id3 = id - GV;
        const int lane = id3 & 63, g = id3 >> 6;
        const int q = lane >> 4, l15 = lane & 15;
        const int ks = g / 20, tile = g % 20;
        const int o = tile * 16 + l15, k0 = ks * 32 + q * 8;
        if (o < OUT_) {
            #pragma unroll
            for (int e = 0; e < 8; ++e) {
                const int k = k0 + e;
                if (k < D1_) o8[e] = f2bf(W[(size_t)o * (D1_ + D2_) + k]);
            }
        }
        *(short8v*)(Bpk + (size_t)id3 * 8) = o8;
    } else {
        const int id4 = id - GV - GB;
        const int lane = id4 & 63, g = id4 >> 6;
        const int q = lane >> 4, l15 = lane & 15;
        const int ks = g / 20, tile = g % 20;
        const int o = tile * 16 + l15, k0 = ks * 32 + q * 8;
        if (o < OUT_) {
            #pragma unroll
            for (int e = 0; e < 8; ++e) {
                const int k = k0 + e;
                if (k < D2_)        o8[e] = f2bf(W[(size_t)o * (D1_ + D2_) + D1_ + k]);
                else if (k == 319)  o8[e] = f2bf(bias[o]);
            }
        }
        *(short8v*)(Wvpk + (size_t)id4 * 8) = o8;
    }
}

// vlin[row][col] = vec . Wv + bias   (4096 x 320, K=320)
__global__ __launch_bounds__(64) void vlin_kernel(
    const short* Vpk, const short* Wvpk, float* vlin)
{
    if (!vlin) { Vpk = g_Vpk; Wvpk = g_Wvpk; vlin = g_vlin; }
    const int mtile = blockIdx.x;           // 0..255
    const int lane = threadIdx.x;
    const int q = lane >> 4, l15 = lane & 15;
    f32x4 acc[20];
    #pragma unroll
    for (int j = 0; j < 20; ++j) acc[j] = {0.f, 0.f, 0.f, 0.f};
    const short* pa = Vpk + (size_t)mtile * KS * FR + lane * 8;
    const short* pb = Wvpk + lane * 8;
    #pragma unroll
    for (int ks = 0; ks < KS; ++ks) {
        const bf16x8 a = *(const bf16x8*)pa; pa += FR;
        #pragma unroll
        for (int j = 0; j < 20; ++j) {
            const bf16x8 b = *(const bf16x8*)(pb + j * FR);
            acc[j] = __builtin_amdgcn_mfma_f32_16x16x32_bf16(a, b, acc[j], 0, 0, 0);
        }
        pb += 20 * FR;
    }
    const int row0 = mtile * 16 + q * 4;
    #pragma unroll
    for (int j = 0; j < 20; ++j)
        #pragma unroll
        for (int r = 0; r < 4; ++r)
            vlin[(size_t)(row0 + r) * 320 + j * 16 + l15] = acc[j][r];
}

__global__ __launch_bounds__(256, 2) void attn_fused(
    const float* __restrict__ seq,   // fp32 [4096,20,300]
    const int*   __restrict__ masks,
    const float* __restrict__ vvec,
    const short* Bpk,
    const float* vlinbuf,
    float*       __restrict__ out)
{
    if (!Bpk) { Bpk = g_Bpk; vlinbuf = g_vlin; }

    __shared__ short Am[5 * KS * FR];     // 51,200 B — bf16 A in fragment layout
    __shared__ float sp[4][BM];           // 1,280 B
    __shared__ float alpha_lds[BM];       // 320 B  — total 52,800 B

    const int tid  = threadIdx.x;
    const int lane = tid & 63;
    const int wv   = tid >> 6;            // 0..3
    const int q    = lane >> 4;
    const int l15  = lane & 15;
    const int blk  = blockIdx.x;

    // ---- Phase 1: fp32 seq tile -> bf16 fragment slabs in LDS ----
    // Fully unrolled, load-all-then-pack: all 13 rounds (26 float4 loads) are
    // issued before any vmcnt drain, so each wave keeps ~832 B/lane in flight
    // (vs 64 B/lane in the old runtime-trip-count loop). acc[][] isn't live
    // yet, so the register lifetimes don't collide with the GEMM accumulator.
    {
        const float* sbase = seq + (size_t)blk * BM * D1_;
        float4 ra[13], rb[13];
        #pragma unroll
        for (int it = 0; it < 13; ++it) {
            const int s = wv + it * 4;
            float4 fa = {0.f, 0.f, 0.f, 0.f}, fb = {0.f, 0.f, 0.f, 0.f};
            if (s < 50) {
                const int tile = s / KS, ks = s % KS;
                const int row = tile * 16 + l15;
                const int k0 = ks * 32 + q * 8;
                const float* p = sbase + (size_t)row * D1_ + k0;
                if (k0 < 296) { fa = *(const float4*)p; fb = *(const float4*)(p + 4); }
                else if (k0 == 296) { fa = *(const float4*)p; }
            }
            ra[it] = fa; rb[it] = fb;
        }
        #pragma unroll
        for (int it = 0; it < 13; ++it) {
            const int s = wv + it * 4;
            if (s < 50) pack_store(Am, s, lane, ra[it], rb[it]);
        }
    }

    // v-vector loads issued before the barrier so their latency hides
    float vj[5];
    #pragma unroll
    for (int j = 0; j < 5; ++j) {
        const int col = wv * 80 + j * 16 + l15;
        vj[j] = (col < OUT_) ? vvec[col] : 0.f;
    }
    __syncthreads();

    // ---- Phase 2: barrier-free GEMM. A from LDS, B from L2 (frag-packed) ----
    f32x4 acc[5][5];
    #pragma unroll
    for (int i = 0; i < 5; ++i)
        #pragma unroll
        for (int j = 0; j < 5; ++j) acc[i][j] = {0.f, 0.f, 0.f, 0.f};

    const short* pb[5];
    #pragma unroll
    for (int j = 0; j < 5; ++j)
        pb[j] = Bpk + (size_t)(wv * 5 + j) * FR + lane * 8;

    #pragma unroll
    for (int ks = 0; ks < KS; ++ks) {
        bf16x8 a[5], b[5];
        #pragma unroll
        for (int i = 0; i < 5; ++i)
            a[i] = *(const bf16x8*)(Am + (((size_t)i * KS + ks) * 64 + lane) * 8);
        #pragma unroll
        for (int j = 0; j < 5; ++j)
            b[j] = *(const bf16x8*)(pb[j] + (size_t)ks * 20 * FR);
        #pragma unroll
        for (int i = 0; i < 5; ++i)
            #pragma unroll
            for (int j = 0; j < 5; ++j)
                acc[i][j] = __builtin_amdgcn_mfma_f32_16x16x32_bf16(a[i], b[j], acc[i][j], 0, 0, 0);
    }

    // ---- epilogue: lin = acc + vlin; score[r] = sum_o tanh(lin) * v[o] ----
    #pragma unroll
    for (int i = 0; i < 5; ++i) {
        #pragma unroll
        for (int r = 0; r < 4; ++r) {
            const int row  = i * 16 + q * 4 + r;       // 0..79
            const int pair = row / 20;
            const float* vl = vlinbuf + (size_t)(blk * PPB + pair) * 320 + wv * 80 + l15;
            float s = 0.f;
            #pragma unroll
            for (int j = 0; j < 5; ++j) {
                const float x = acc[i][j][r] + vl[j * 16];
                const float e = __expf(2.f * x);       // tanh(x) = 1 - 2/(e^{2x}+1)
                s += (1.f - 2.f / (e + 1.f)) * vj[j];
            }
            s += __shfl_xor(s, 1, 64);
            s += __shfl_xor(s, 2, 64);
            s += __shfl_xor(s, 4, 64);
            s += __shfl_xor(s, 8, 64);                 // sum 16 cols of tile
            if (l15 == 0) sp[wv][row] = s;
        }
    }
    __syncthreads();

    // ---- wave-parallel masked softmax: 32 lanes per pair (128 threads) ----
    if (tid < 128) {
        const int p = tid >> 5;            // pair 0..3
        const int w = tid & 31;            // 0..31, active w<20
        float s;
        if (w < WL_) {
            const int row = p * WL_ + w;
            const float sc = sp[0][row] + sp[1][row] + sp[2][row] + sp[3][row];
            const int mk = masks[(size_t)(blk * PPB + p) * WL_ + w];
            s = (mk == 0) ? NEG_INF : sc;
        } else {
            s = -INFINITY;                 // padding lanes: exp(-inf)=0
        }
        float m = s;
        #pragma unroll
        for (int off = 16; off; off >>= 1)
            m = fmaxf(m, __shfl_xor(m, off, 32));
        const float e = __expf(s - m);
        float sum = e;
        #pragma unroll
        for (int off = 16; off; off >>= 1)
            sum += __shfl_xor(sum, off, 32);
        if (w < WL_) alpha_lds[p * WL_ + w] = e / sum;
    }
    __syncthreads();

    // ---- weighted sum from the bf16 LDS fragments (staggered w to kill
    //      same-bank-quad collisions across the 38 chunk-threads per pair) ----
    if (tid < PPB * 38) {
        const int p = tid / 38, ch = tid % 38;
        const int ks2 = ch >> 2, q2 = ch & 3;
        const int wst = ch % WL_;
        float o8[8] = {0.f, 0.f, 0.f, 0.f, 0.f, 0.f, 0.f, 0.f};
        #pragma unroll
        for (int wi = 0; wi < WL_; ++wi) {
            int w = wst + wi; if (w >= WL_) w -= WL_;
            const int row = p * WL_ + w;
            const int tl = row >> 4, l = row & 15;
            const bf16x8 s8 = *(const bf16x8*)(Am + (((size_t)tl * KS + ks2) * 64 + q2 * 16 + l) * 8);
            const float a = alpha_lds[row];
            #pragma unroll
            for (int e2 = 0; e2 < 8; ++e2) o8[e2] += a * bf2f(s8[e2]);
        }
        const int d0 = ch * 8, gp = blk * PPB + p;
        float* dst = out + (size_t)gp * OUT_ + d0;
        if (d0 + 8 <= OUT_) {
            *(float4*)dst       = {o8[0], o8[1], o8[2], o8[3]};
            *(float4*)(dst + 4) = {o8[4], o8[5], o8[6], o8[7]};
        } else {                                   // d0 == 296: last 4 only
            *(float4*)dst = {o8[0], o8[1], o8[2], o8[3]};
        }
    }
}

extern "C" void kernel_launch(void* const* d_in, const int* in_sizes, int n_in,
                              void* d_out, int out_size, void* d_ws, size_t ws_size,
                              hipStream_t stream) {
    const float* seq   = (const float*)d_in[0];
    const float* vec   = (const float*)d_in[1];
    const int*   masks = (const int*)d_in[2];
    const float* W     = (const float*)d_in[3];
    const float* b     = (const float*)d_in[4];
    const float* v     = (const float*)d_in[5];
    float* out = (float*)d_out;

    // Carve scratch out of the harness workspace (avoids __device__ globals,
    // which may be snapshot/restored by the harness's reset machinery).
    constexpr size_t SZ_B = sizeof(short) * (size_t)KS * 20 * FR;   // 204,800
    constexpr size_t SZ_V = sizeof(short) * (size_t)256 * KS * FR;  // 2,621,440
    constexpr size_t SZ_L = sizeof(float) * (size_t)BS_ * 320;      // 5,242,880
    constexpr size_t NEED = SZ_B * 2 + SZ_V + SZ_L;                 // 8,273,920
    short *Bpk = nullptr, *Wvpk = nullptr, *Vpk = nullptr;
    float *vlin = nullptr;
    if (d_ws && ws_size >= NEED) {
        char* p = (char*)d_ws;
        Bpk  = (short*)p; p += SZ_B;
        Wvpk = (short*)p; p += SZ_B;
        Vpk  = (short*)p; p += SZ_V;
        vlin = (float*)p;
    }

    prep_small<<<(GT + 255) / 256, 256, 0, stream>>>(vec, W, b, Bpk, Vpk, Wvpk);
    vlin_kernel<<<256, 64, 0, stream>>>(Vpk, Wvpk, vlin);
    attn_fused<<<NBLK, 256, 0, stream>>>(seq, masks, v, Bpk, vlin, out);
}

// Round 2
// 211.971 us; speedup vs baseline: 1.1965x; 1.1526x over previous
//
#include <hip/hip_runtime.h>
#include <math.h>

#define NEG_INF -1000000000.0f

// Problem constants
#define WL_  20
#define D1_  300
#define D2_  300
#define OUT_ 300
#define BS_  4096                 // (b,s) pairs
#define PPB  4                    // pairs per block
#define NBLK (BS_ / PPB)          // 1024 blocks
#define BM   80                   // rows per block = 5 M-tiles
#define KS   10                   // k-steps of 32 (K = 320)
#define FR   512                  // shorts per fragment slab [64 lanes][8]

typedef __attribute__((ext_vector_type(8))) short bf16x8;
typedef __attribute__((ext_vector_type(8))) short short8v;
typedef __attribute__((ext_vector_type(4))) float f32x4;
typedef __attribute__((ext_vector_type(4))) unsigned int uint4v;

// Fallback storage (only used if workspace too small). Preferred path: d_ws.
__device__ short g_Bpk[KS * 20 * FR];
__device__ short g_Vpk[256 * KS * FR];
__device__ short g_Wvpk[KS * 20 * FR];
__device__ float g_vlin[(size_t)BS_ * 320];

__device__ inline short f2bf(float f) {
    unsigned u = __float_as_uint(f);
    u += 0x7FFFu + ((u >> 16) & 1u);   // RNE
    return (short)(u >> 16);
}
__device__ inline float bf2f(short s) {
    return __uint_as_float(((unsigned)(unsigned short)s) << 16);
}

// round-half-up fp32->bf16 pack of 8 floats -> 16B fragment store
__device__ inline void pack_store(short* Am, int s, int lane, float4 fa, float4 fb) {
    unsigned u0 = __float_as_uint(fa.x) + 0x8000u;
    unsigned u1 = __float_as_uint(fa.y) + 0x8000u;
    unsigned u2 = __float_as_uint(fa.z) + 0x8000u;
    unsigned u3 = __float_as_uint(fa.w) + 0x8000u;
    unsigned u4 = __float_as_uint(fb.x) + 0x8000u;
    unsigned u5 = __float_as_uint(fb.y) + 0x8000u;
    unsigned u6 = __float_as_uint(fb.z) + 0x8000u;
    unsigned u7 = __float_as_uint(fb.w) + 0x8000u;
    uint4v w;
    w.x = __builtin_amdgcn_perm(u1, u0, 0x07060302u);
    w.y = __builtin_amdgcn_perm(u3, u2, 0x07060302u);
    w.z = __builtin_amdgcn_perm(u5, u4, 0x07060302u);
    w.w = __builtin_amdgcn_perm(u7, u6, 0x07060302u);
    *(uint4v*)(Am + ((size_t)s * 64 + lane) * 8) = w;
}

#define GV (256 * KS * 64)        // 163,840 vec fragment-groups
#define GB (KS * 20 * 64)         // 12,800  W fragment-groups
#define GT (GV + GB + GB)

__global__ __launch_bounds__(256) void prep_small(
    const float* __restrict__ vec, const float* __restrict__ W,
    const float* __restrict__ bias,
    short* Bpk, short* Vpk, short* Wvpk)
{
    if (!Bpk) { Bpk = g_Bpk; Vpk = g_Vpk; Wvpk = g_Wvpk; }
    const int id = blockIdx.x * 256 + threadIdx.x;
    if (id >= GT) return;
    short8v o8 = {0, 0, 0, 0, 0, 0, 0, 0};
    if (id < GV) {
        const int lane = id & 63, g = id >> 6;
        const int q = lane >> 4, l15 = lane & 15;
        const int ks = g % KS, mtile = g / KS;
        const int row = mtile * 16 + l15;          // pair index < 4096
        const int k0 = ks * 32 + q * 8;
        const float* s = vec + (size_t)row * D2_ + k0;
        #pragma unroll
        for (int e = 0; e < 8; ++e) {
            const int k = k0 + e;
            if (k < D2_) o8[e] = f2bf(s[e]);
            else if (k == 319) o8[e] = (short)0x3F80;   // 1.0 (bias column)
        }
        *(short8v*)(Vpk + (size_t)id * 8) = o8;
    } else if (id < GV + GB) {
        const int id3 = id - GV;
        const int lane = id3 & 63, g = id3 >> 6;
        const int q = lane >> 4, l15 = lane & 15;
        const int ks = g / 20, tile = g % 20;
        const int o = tile * 16 + l15, k0 = ks * 32 + q * 8;
        if (o < OUT_) {
            #pragma unroll
            for (int e = 0; e < 8; ++e) {
                const int k = k0 + e;
                if (k < D1_) o8[e] = f2bf(W[(size_t)o * (D1_ + D2_) + k]);
            }
        }
        *(short8v*)(Bpk + (size_t)id3 * 8) = o8;
    } else {
        const int id4 = id - GV - GB;
        const int lane = id4 & 63, g = id4 >> 6;
        const int q = lane >> 4, l15 = lane & 15;
        const int ks = g / 20, tile = g % 20;
        const int o = tile * 16 + l15, k0 = ks * 32 + q * 8;
        if (o < OUT_) {
            #pragma unroll
            for (int e = 0; e < 8; ++e) {
                const int k = k0 + e;
                if (k < D2_)        o8[e] = f2bf(W[(size_t)o * (D1_ + D2_) + D1_ + k]);
                else if (k == 319)  o8[e] = f2bf(bias[o]);
            }
        }
        *(short8v*)(Wvpk + (size_t)id4 * 8) = o8;
    }
}

// vlin[row][col] = vec . Wv + bias   (4096 x 320, K=320)
// 4 waves/block: wave wv owns j-tiles wv*5 .. wv*5+4 (was 1 wave doing all 20
// -> 1 wave/CU, pure latency exposure; now 4 waves/CU and 1/4 the per-wave
// dependent-load chain).
__global__ __launch_bounds__(256) void vlin_kernel(
    const short* Vpk, const short* Wvpk, float* vlin)
{
    if (!vlin) { Vpk = g_Vpk; Wvpk = g_Wvpk; vlin = g_vlin; }
    const int mtile = blockIdx.x;           // 0..255
    const int tid  = threadIdx.x;
    const int lane = tid & 63;
    const int wv   = tid >> 6;              // 0..3 -> j-tile group
    const int q = lane >> 4, l15 = lane & 15;
    f32x4 acc[5];
    #pragma unroll
    for (int j = 0; j < 5; ++j) acc[j] = {0.f, 0.f, 0.f, 0.f};
    const short* pa = Vpk + (size_t)mtile * KS * FR + lane * 8;
    const short* pb = Wvpk + (size_t)(wv * 5) * FR + lane * 8;
    #pragma unroll
    for (int ks = 0; ks < KS; ++ks) {
        const bf16x8 a = *(const bf16x8*)pa; pa += FR;
        #pragma unroll
        for (int j = 0; j < 5; ++j) {
            const bf16x8 b = *(const bf16x8*)(pb + j * FR);
            acc[j] = __builtin_amdgcn_mfma_f32_16x16x32_bf16(a, b, acc[j], 0, 0, 0);
        }
        pb += 20 * FR;
    }
    const int row0 = mtile * 16 + q * 4;
    #pragma unroll
    for (int j = 0; j < 5; ++j)
        #pragma unroll
        for (int r = 0; r < 4; ++r)
            vlin[(size_t)(row0 + r) * 320 + (wv * 5 + j) * 16 + l15] = acc[j][r];
}

// 3 blocks/CU (LDS 53,248 B/block * 3 = 159,744 <= 163,840; VGPR cap 170).
__global__ __launch_bounds__(256, 3) void attn_fused(
    const float* __restrict__ seq,   // fp32 [4096,20,300]
    const int*   __restrict__ masks,
    const float* __restrict__ vvec,
    const short* Bpk,
    const float* vlinbuf,
    float*       __restrict__ out)
{
    if (!Bpk) { Bpk = g_Bpk; vlinbuf = g_vlin; }

    __shared__ short Am[5 * KS * FR];     // 51,200 B — bf16 A in fragment layout
    __shared__ float sp[4][BM];           // 1,280 B
    __shared__ float alpha_lds[BM];       // 320 B  — total 52,800 B

    const int tid  = threadIdx.x;
    const int lane = tid & 63;
    const int wv   = tid >> 6;            // 0..3
    const int q    = lane >> 4;
    const int l15  = lane & 15;
    const int blk  = blockIdx.x;

    // ---- Phase 1: fp32 seq tile -> bf16 fragment slabs in LDS ----
    // Fully unrolled, load-all-then-pack (compile-time trip counts so the
    // loads pipeline; acc[][] not yet live so register lifetimes don't clash).
    {
        const float* sbase = seq + (size_t)blk * BM * D1_;
        float4 ra[13], rb[13];
        #pragma unroll
        for (int it = 0; it < 13; ++it) {
            const int s = wv + it * 4;
            float4 fa = {0.f, 0.f, 0.f, 0.f}, fb = {0.f, 0.f, 0.f, 0.f};
            if (s < 50) {
                const int tile = s / KS, ks = s % KS;
                const int row = tile * 16 + l15;
                const int k0 = ks * 32 + q * 8;
                const float* p = sbase + (size_t)row * D1_ + k0;
                if (k0 < 296) { fa = *(const float4*)p; fb = *(const float4*)(p + 4); }
                else if (k0 == 296) { fa = *(const float4*)p; }
            }
            ra[it] = fa; rb[it] = fb;
        }
        #pragma unroll
        for (int it = 0; it < 13; ++it) {
            const int s = wv + it * 4;
            if (s < 50) pack_store(Am, s, lane, ra[it], rb[it]);
        }
    }

    // v-vector + vlin register preloads: issued before the barrier so their
    // (L2/L3) latency hides under the phase-1 drain + barrier. Removes 100
    // per-thread global loads from the post-GEMM critical path.
    float vj[5];
    #pragma unroll
    for (int j = 0; j < 5; ++j) {
        const int col = wv * 80 + j * 16 + l15;
        vj[j] = (col < OUT_) ? vvec[col] : 0.f;
    }
    float vlp[4][5];
    #pragma unroll
    for (int p = 0; p < 4; ++p)
        #pragma unroll
        for (int j = 0; j < 5; ++j)
            vlp[p][j] = vlinbuf[(size_t)(blk * PPB + p) * 320 + wv * 80 + j * 16 + l15];
    __syncthreads();

    // ---- Phase 2: barrier-free GEMM. A from LDS, B from L2 (frag-packed) ----
    f32x4 acc[5][5];
    #pragma unroll
    for (int i = 0; i < 5; ++i)
        #pragma unroll
        for (int j = 0; j < 5; ++j) acc[i][j] = {0.f, 0.f, 0.f, 0.f};

    const short* pb[5];
    #pragma unroll
    for (int j = 0; j < 5; ++j)
        pb[j] = Bpk + (size_t)(wv * 5 + j) * FR + lane * 8;

    #pragma unroll
    for (int ks = 0; ks < KS; ++ks) {
        bf16x8 a[5], b[5];
        #pragma unroll
        for (int i = 0; i < 5; ++i)
            a[i] = *(const bf16x8*)(Am + (((size_t)i * KS + ks) * 64 + lane) * 8);
        #pragma unroll
        for (int j = 0; j < 5; ++j)
            b[j] = *(const bf16x8*)(pb[j] + (size_t)ks * 20 * FR);
        #pragma unroll
        for (int i = 0; i < 5; ++i)
            #pragma unroll
            for (int j = 0; j < 5; ++j)
                acc[i][j] = __builtin_amdgcn_mfma_f32_16x16x32_bf16(a[i], b[j], acc[i][j], 0, 0, 0);
    }

    // ---- epilogue: lin = acc + vlin; score[r] = sum_o tanh(lin) * v[o] ----
    // Tile i spans at most 2 of the 4 (b,s) pairs (compile-time pLo/pHi);
    // runtime pair choice is a single cndmask per element, registers only.
    #pragma unroll
    for (int i = 0; i < 5; ++i) {
        const int pLo = (16 * i) / 20;
        const int pHi = (16 * i + 15) / 20;
        #pragma unroll
        for (int r = 0; r < 4; ++r) {
            const int row = i * 16 + q * 4 + r;        // 0..79
            const bool hi = (row >= 20 * pHi);
            float s = 0.f;
            #pragma unroll
            for (int j = 0; j < 5; ++j) {
                const float vlv = (pLo == pHi) ? vlp[pLo][j]
                                               : (hi ? vlp[pHi][j] : vlp[pLo][j]);
                const float x = acc[i][j][r] + vlv;
                const float e = __expf(2.f * x);       // tanh(x) = 1 - 2/(e^{2x}+1)
                s += (1.f - 2.f / (e + 1.f)) * vj[j];
            }
            s += __shfl_xor(s, 1, 64);
            s += __shfl_xor(s, 2, 64);
            s += __shfl_xor(s, 4, 64);
            s += __shfl_xor(s, 8, 64);                 // sum 16 cols of tile
            if (l15 == 0) sp[wv][row] = s;
        }
    }
    __syncthreads();

    // ---- wave-parallel masked softmax: 32 lanes per pair (128 threads) ----
    if (tid < 128) {
        const int p = tid >> 5;            // pair 0..3
        const int w = tid & 31;            // 0..31, active w<20
        float s;
        if (w < WL_) {
            const int row = p * WL_ + w;
            const float sc = sp[0][row] + sp[1][row] + sp[2][row] + sp[3][row];
            const int mk = masks[(size_t)(blk * PPB + p) * WL_ + w];
            s = (mk == 0) ? NEG_INF : sc;
        } else {
            s = -INFINITY;                 // padding lanes: exp(-inf)=0
        }
        float m = s;
        #pragma unroll
        for (int off = 16; off; off >>= 1)
            m = fmaxf(m, __shfl_xor(m, off, 32));
        const float e = __expf(s - m);
        float sum = e;
        #pragma unroll
        for (int off = 16; off; off >>= 1)
            sum += __shfl_xor(sum, off, 32);
        if (w < WL_) alpha_lds[p * WL_ + w] = e / sum;
    }
    __syncthreads();

    // ---- weighted sum from the bf16 LDS fragments (staggered w to kill
    //      same-bank-quad collisions across the 38 chunk-threads per pair) ----
    if (tid < PPB * 38) {
        const int p = tid / 38, ch = tid % 38;
        const int ks2 = ch >> 2, q2 = ch & 3;
        const int wst = ch % WL_;
        float o8[8] = {0.f, 0.f, 0.f, 0.f, 0.f, 0.f, 0.f, 0.f};
        #pragma unroll
        for (int wi = 0; wi < WL_; ++wi) {
            int w = wst + wi; if (w >= WL_) w -= WL_;
            const int row = p * WL_ + w;
            const int tl = row >> 4, l = row & 15;
            const bf16x8 s8 = *(const bf16x8*)(Am + (((size_t)tl * KS + ks2) * 64 + q2 * 16 + l) * 8);
            const float a = alpha_lds[row];
            #pragma unroll
            for (int e2 = 0; e2 < 8; ++e2) o8[e2] += a * bf2f(s8[e2]);
        }
        const int d0 = ch * 8, gp = blk * PPB + p;
        float* dst = out + (size_t)gp * OUT_ + d0;
        if (d0 + 8 <= OUT_) {
            *(float4*)dst       = {o8[0], o8[1], o8[2], o8[3]};
            *(float4*)(dst + 4) = {o8[4], o8[5], o8[6], o8[7]};
        } else {                                   // d0 == 296: last 4 only
            *(float4*)dst = {o8[0], o8[1], o8[2], o8[3]};
        }
    }
}

extern "C" void kernel_launch(void* const* d_in, const int* in_sizes, int n_in,
                              void* d_out, int out_size, void* d_ws, size_t ws_size,
                              hipStream_t stream) {
    const float* seq   = (const float*)d_in[0];
    const float* vec   = (const float*)d_in[1];
    const int*   masks = (const int*)d_in[2];
    const float* W     = (const float*)d_in[3];
    const float* b     = (const float*)d_in[4];
    const float* v     = (const float*)d_in[5];
    float* out = (float*)d_out;

    // Carve scratch out of the harness workspace (avoids __device__ globals,
    // which may be snapshot/restored by the harness's reset machinery).
    constexpr size_t SZ_B = sizeof(short) * (size_t)KS * 20 * FR;   // 204,800
    constexpr size_t SZ_V = sizeof(short) * (size_t)256 * KS * FR;  // 2,621,440
    constexpr size_t SZ_L = sizeof(float) * (size_t)BS_ * 320;      // 5,242,880
    constexpr size_t NEED = SZ_B * 2 + SZ_V + SZ_L;                 // 8,273,920
    short *Bpk = nullptr, *Wvpk = nullptr, *Vpk = nullptr;
    float *vlin = nullptr;
    if (d_ws && ws_size >= NEED) {
        char* p = (char*)d_ws;
        Bpk  = (short*)p; p += SZ_B;
        Wvpk = (short*)p; p += SZ_B;
        Vpk  = (short*)p; p += SZ_V;
        vlin = (float*)p;
    }

    prep_small<<<(GT + 255) / 256, 256, 0, stream>>>(vec, W, b, Bpk, Vpk, Wvpk);
    vlin_kernel<<<256, 256, 0, stream>>>(Vpk, Wvpk, vlin);
    attn_fused<<<NBLK, 256, 0, stream>>>(seq, masks, v, Bpk, vlin, out);
}

// Round 3
// 210.955 us; speedup vs baseline: 1.2022x; 1.0048x over previous
//
#include <hip/hip_runtime.h>
#include <math.h>

#define NEG_INF -1000000000.0f

// Problem constants
#define WL_  20
#define D1_  300
#define D2_  300
#define OUT_ 300
#define BS_  4096                 // (b,s) pairs
#define PPB  4                    // pairs per block
#define NBLK (BS_ / PPB)          // 1024 blocks
#define BM   80                   // rows per block = 5 M-tiles
#define KS   10                   // k-steps of 32 (K = 320)
#define FR   512                  // shorts per fragment slab [64 lanes][8]

typedef __attribute__((ext_vector_type(8))) short bf16x8;
typedef __attribute__((ext_vector_type(8))) short short8v;
typedef __attribute__((ext_vector_type(4))) float f32x4;
typedef __attribute__((ext_vector_type(4))) unsigned int uint4v;

// Fallback storage (only used if workspace too small). Preferred path: d_ws.
__device__ short g_Bpk[KS * 20 * FR];
__device__ short g_Wvpk[KS * 20 * FR];

__device__ inline short f2bf(float f) {
    unsigned u = __float_as_uint(f);
    u += 0x7FFFu + ((u >> 16) & 1u);   // RNE
    return (short)(u >> 16);
}
__device__ inline float bf2f(short s) {
    return __uint_as_float(((unsigned)(unsigned short)s) << 16);
}

// round-half-up fp32->bf16 pack of 8 floats -> 16B fragment store
__device__ inline void pack_store(short* Am, int s, int lane, float4 fa, float4 fb) {
    unsigned u0 = __float_as_uint(fa.x) + 0x8000u;
    unsigned u1 = __float_as_uint(fa.y) + 0x8000u;
    unsigned u2 = __float_as_uint(fa.z) + 0x8000u;
    unsigned u3 = __float_as_uint(fa.w) + 0x8000u;
    unsigned u4 = __float_as_uint(fb.x) + 0x8000u;
    unsigned u5 = __float_as_uint(fb.y) + 0x8000u;
    unsigned u6 = __float_as_uint(fb.z) + 0x8000u;
    unsigned u7 = __float_as_uint(fb.w) + 0x8000u;
    uint4v w;
    w.x = __builtin_amdgcn_perm(u1, u0, 0x07060302u);
    w.y = __builtin_amdgcn_perm(u3, u2, 0x07060302u);
    w.z = __builtin_amdgcn_perm(u5, u4, 0x07060302u);
    w.w = __builtin_amdgcn_perm(u7, u6, 0x07060302u);
    *(uint4v*)(Am + ((size_t)s * 64 + lane) * 8) = w;
}

#define GB (KS * 20 * 64)         // 12,800 W fragment-groups per matrix
#define GT2 (GB + GB)             // 25,600 total -> 100 blocks

// Packs only the two weight matrices now (vec packing + vlin GEMM moved into
// attn_fused). 100 blocks instead of 740.
__global__ __launch_bounds__(256) void prep_small(
    const float* __restrict__ W, const float* __restrict__ bias,
    short* Bpk, short* Wvpk)
{
    if (!Bpk) { Bpk = g_Bpk; Wvpk = g_Wvpk; }
    const int id = blockIdx.x * 256 + threadIdx.x;
    if (id >= GT2) return;
    short8v o8 = {0, 0, 0, 0, 0, 0, 0, 0};
    if (id < GB) {
        const int lane = id & 63, g = id >> 6;
        const int q = lane >> 4, l15 = lane & 15;
        const int ks = g / 20, tile = g % 20;
        const int o = tile * 16 + l15, k0 = ks * 32 + q * 8;
        if (o < OUT_) {
            #pragma unroll
            for (int e = 0; e < 8; ++e) {
                const int k = k0 + e;
                if (k < D1_) o8[e] = f2bf(W[(size_t)o * (D1_ + D2_) + k]);
            }
        }
        *(short8v*)(Bpk + (size_t)id * 8) = o8;
    } else {
        const int id4 = id - GB;
        const int lane = id4 & 63, g = id4 >> 6;
        const int q = lane >> 4, l15 = lane & 15;
        const int ks = g / 20, tile = g % 20;
        const int o = tile * 16 + l15, k0 = ks * 32 + q * 8;
        if (o < OUT_) {
            #pragma unroll
            for (int e = 0; e < 8; ++e) {
                const int k = k0 + e;
                if (k < D2_)        o8[e] = f2bf(W[(size_t)o * (D1_ + D2_) + D1_ + k]);
                else if (k == 319)  o8[e] = f2bf(bias[o]);
            }
        }
        *(short8v*)(Wvpk + (size_t)id4 * 8) = o8;
    }
}

// (256,2): the empirically spill-free register regime (r2's (256,3) made the
// allocator target 84 VGPRs and spill 27 MB/dispatch of scratch traffic).
// LDS 52.8 KB still allows 3 blocks/CU if the allocation lands <= 168 regs.
__global__ __launch_bounds__(256, 2) void attn_fused(
    const float* __restrict__ seq,   // fp32 [4096,20,300]
    const float* __restrict__ vec,   // fp32 [4096,300]
    const int*   __restrict__ masks,
    const float* __restrict__ vvec,
    const short* Bpk, const short* Wvpk,
    float*       __restrict__ out)
{
    if (!Bpk) { Bpk = g_Bpk; Wvpk = g_Wvpk; }

    __shared__ short Am[5 * KS * FR];     // 51,200 B — bf16 A in fragment layout
    __shared__ float sp[4][BM];           // 1,280 B
    __shared__ float alpha_lds[BM];       // 320 B  — total 52,800 B

    const int tid  = threadIdx.x;
    const int lane = tid & 63;
    const int wv   = tid >> 6;            // 0..3
    const int q    = lane >> 4;
    const int l15  = lane & 15;
    const int blk  = blockIdx.x;

    // ---- Phase 1: fp32 seq tile -> bf16 fragment slabs in LDS ----
    // Fully unrolled, load-all-then-pack (compile-time trip counts so the
    // loads pipeline; acc[][] not yet live so register lifetimes don't clash).
    {
        const float* sbase = seq + (size_t)blk * BM * D1_;
        float4 ra[13], rb[13];
        #pragma unroll
        for (int it = 0; it < 13; ++it) {
            const int s = wv + it * 4;
            float4 fa = {0.f, 0.f, 0.f, 0.f}, fb = {0.f, 0.f, 0.f, 0.f};
            if (s < 50) {
                const int tile = s / KS, ks = s % KS;
                const int row = tile * 16 + l15;
                const int k0 = ks * 32 + q * 8;
                const float* p = sbase + (size_t)row * D1_ + k0;
                if (k0 < 296) { fa = *(const float4*)p; fb = *(const float4*)(p + 4); }
                else if (k0 == 296) { fa = *(const float4*)p; }
            }
            ra[it] = fa; rb[it] = fb;
        }
        #pragma unroll
        for (int it = 0; it < 13; ++it) {
            const int s = wv + it * 4;
            if (s < 50) pack_store(Am, s, lane, ra[it], rb[it]);
        }
    }

    // v-vector loads issued before the barrier so their latency hides
    float vj[5];
    #pragma unroll
    for (int j = 0; j < 5; ++j) {
        const int col = wv * 80 + j * 16 + l15;
        vj[j] = (col < OUT_) ? vvec[col] : 0.f;
    }

    // ---- in-block vlin mini-GEMM: lin_vec[pair][col] = vec . Wv + bias ----
    // M-tile rows 0..3 = the block's 4 (b,s) pairs (rows 4..15 zero). Same
    // fragment math / rounding as the old standalone vlin kernel, so the
    // numerics are bit-identical; reuses the Wvpk B-fragments from L2.
    f32x4 vacc[5];
    #pragma unroll
    for (int j = 0; j < 5; ++j) vacc[j] = {0.f, 0.f, 0.f, 0.f};
    {
        const short* pwb = Wvpk + (size_t)(wv * 5) * FR + lane * 8;
        const float* vp = vec + (size_t)(blk * PPB + (l15 & 3)) * D2_;
        #pragma unroll
        for (int ks = 0; ks < KS; ++ks) {
            const int k0 = ks * 32 + q * 8;
            short8v av = {0, 0, 0, 0, 0, 0, 0, 0};
            if (l15 < PPB) {
                #pragma unroll
                for (int e = 0; e < 8; ++e) {
                    const int k = k0 + e;
                    if (k < D2_)       av[e] = f2bf(vp[k]);
                    else if (k == 319) av[e] = (short)0x3F80;   // 1.0 bias col
                }
            }
            #pragma unroll
            for (int j = 0; j < 5; ++j) {
                const bf16x8 b = *(const bf16x8*)(pwb + j * FR);
                vacc[j] = __builtin_amdgcn_mfma_f32_16x16x32_bf16(
                    (bf16x8)av, b, vacc[j], 0, 0, 0);
            }
            pwb += 20 * FR;
        }
    }
    // C layout: col=lane&15, row=(lane>>4)*4+reg -> row p (p<4) lives in
    // lane l15=col (q=0), reg p. Broadcast each pair's value to all lanes.
    float vlp[4][5];
    #pragma unroll
    for (int p = 0; p < 4; ++p)
        #pragma unroll
        for (int j = 0; j < 5; ++j)
            vlp[p][j] = __shfl(vacc[j][p], l15, 64);
    __syncthreads();

    // ---- Phase 2: barrier-free GEMM. A from LDS, B from L2 (frag-packed) ----
    f32x4 acc[5][5];
    #pragma unroll
    for (int i = 0; i < 5; ++i)
        #pragma unroll
        for (int j = 0; j < 5; ++j) acc[i][j] = {0.f, 0.f, 0.f, 0.f};

    const short* pb[5];
    #pragma unroll
    for (int j = 0; j < 5; ++j)
        pb[j] = Bpk + (size_t)(wv * 5 + j) * FR + lane * 8;

    #pragma unroll
    for (int ks = 0; ks < KS; ++ks) {
        bf16x8 a[5], b[5];
        #pragma unroll
        for (int i = 0; i < 5; ++i)
            a[i] = *(const bf16x8*)(Am + (((size_t)i * KS + ks) * 64 + lane) * 8);
        #pragma unroll
        for (int j = 0; j < 5; ++j)
            b[j] = *(const bf16x8*)(pb[j] + (size_t)ks * 20 * FR);
        #pragma unroll
        for (int i = 0; i < 5; ++i)
            #pragma unroll
            for (int j = 0; j < 5; ++j)
                acc[i][j] = __builtin_amdgcn_mfma_f32_16x16x32_bf16(a[i], b[j], acc[i][j], 0, 0, 0);
    }

    // ---- epilogue: lin = acc + vlin; score[r] = sum_o tanh(lin) * v[o] ----
    // Tile i spans at most 2 of the 4 (b,s) pairs (compile-time pLo/pHi);
    // runtime pair choice is a single cndmask per element, registers only.
    #pragma unroll
    for (int i = 0; i < 5; ++i) {
        const int pLo = (16 * i) / 20;
        const int pHi = (16 * i + 15) / 20;
        #pragma unroll
        for (int r = 0; r < 4; ++r) {
            const int row = i * 16 + q * 4 + r;        // 0..79
            const bool hi = (row >= 20 * pHi);
            float s = 0.f;
            #pragma unroll
            for (int j = 0; j < 5; ++j) {
                const float vlv = (pLo == pHi) ? vlp[pLo][j]
                                               : (hi ? vlp[pHi][j] : vlp[pLo][j]);
                const float x = acc[i][j][r] + vlv;
                const float e = __expf(2.f * x);       // tanh(x) = 1 - 2/(e^{2x}+1)
                s += (1.f - 2.f / (e + 1.f)) * vj[j];
            }
            s += __shfl_xor(s, 1, 64);
            s += __shfl_xor(s, 2, 64);
            s += __shfl_xor(s, 4, 64);
            s += __shfl_xor(s, 8, 64);                 // sum 16 cols of tile
            if (l15 == 0) sp[wv][row] = s;
        }
    }
    __syncthreads();

    // ---- wave-parallel masked softmax: 32 lanes per pair (128 threads) ----
    if (tid < 128) {
        const int p = tid >> 5;            // pair 0..3
        const int w = tid & 31;            // 0..31, active w<20
        float s;
        if (w < WL_) {
            const int row = p * WL_ + w;
            const float sc = sp[0][row] + sp[1][row] + sp[2][row] + sp[3][row];
            const int mk = masks[(size_t)(blk * PPB + p) * WL_ + w];
            s = (mk == 0) ? NEG_INF : sc;
        } else {
            s = -INFINITY;                 // padding lanes: exp(-inf)=0
        }
        float m = s;
        #pragma unroll
        for (int off = 16; off; off >>= 1)
            m = fmaxf(m, __shfl_xor(m, off, 32));
        const float e = __expf(s - m);
        float sum = e;
        #pragma unroll
        for (int off = 16; off; off >>= 1)
            sum += __shfl_xor(sum, off, 32);
        if (w < WL_) alpha_lds[p * WL_ + w] = e / sum;
    }
    __syncthreads();

    // ---- weighted sum from the bf16 LDS fragments (staggered w to kill
    //      same-bank-quad collisions across the 38 chunk-threads per pair) ----
    if (tid < PPB * 38) {
        const int p = tid / 38, ch = tid % 38;
        const int ks2 = ch >> 2, q2 = ch & 3;
        const int wst = ch % WL_;
        float o8[8] = {0.f, 0.f, 0.f, 0.f, 0.f, 0.f, 0.f, 0.f};
        #pragma unroll
        for (int wi = 0; wi < WL_; ++wi) {
            int w = wst + wi; if (w >= WL_) w -= WL_;
            const int row = p * WL_ + w;
            const int tl = row >> 4, l = row & 15;
            const bf16x8 s8 = *(const bf16x8*)(Am + (((size_t)tl * KS + ks2) * 64 + q2 * 16 + l) * 8);
            const float a = alpha_lds[row];
            #pragma unroll
            for (int e2 = 0; e2 < 8; ++e2) o8[e2] += a * bf2f(s8[e2]);
        }
        const int d0 = ch * 8, gp = blk * PPB + p;
        float* dst = out + (size_t)gp * OUT_ + d0;
        if (d0 + 8 <= OUT_) {
            *(float4*)dst       = {o8[0], o8[1], o8[2], o8[3]};
            *(float4*)(dst + 4) = {o8[4], o8[5], o8[6], o8[7]};
        } else {                                   // d0 == 296: last 4 only
            *(float4*)dst = {o8[0], o8[1], o8[2], o8[3]};
        }
    }
}

extern "C" void kernel_launch(void* const* d_in, const int* in_sizes, int n_in,
                              void* d_out, int out_size, void* d_ws, size_t ws_size,
                              hipStream_t stream) {
    const float* seq   = (const float*)d_in[0];
    const float* vec   = (const float*)d_in[1];
    const int*   masks = (const int*)d_in[2];
    const float* W     = (const float*)d_in[3];
    const float* b     = (const float*)d_in[4];
    const float* v     = (const float*)d_in[5];
    float* out = (float*)d_out;

    // Carve scratch out of the harness workspace (avoids __device__ globals,
    // which may be snapshot/restored by the harness's reset machinery).
    constexpr size_t SZ_B = sizeof(short) * (size_t)KS * 20 * FR;   // 204,800
    constexpr size_t NEED = SZ_B * 2;                               // 409,600
    short *Bpk = nullptr, *Wvpk = nullptr;
    if (d_ws && ws_size >= NEED) {
        char* p = (char*)d_ws;
        Bpk  = (short*)p; p += SZ_B;
        Wvpk = (short*)p;
    }

    prep_small<<<(GT2 + 255) / 256, 256, 0, stream>>>(W, b, Bpk, Wvpk);
    attn_fused<<<NBLK, 256, 0, stream>>>(seq, vec, masks, v, Bpk, Wvpk, out);
}

// Round 4
// 197.762 us; speedup vs baseline: 1.2824x; 1.0667x over previous
//
#include <hip/hip_runtime.h>
#include <math.h>

#define NEG_INF -1000000000.0f

// Problem constants
#define WL_  20
#define D1_  300
#define D2_  300
#define OUT_ 300
#define BS_  4096                 // (b,s) pairs
#define PPB  2                    // pairs per block (was 4; halved to cut LDS)
#define NBLK (BS_ / PPB)          // 2048 blocks
#define BM   40                   // rows per block (2 pairs x 20 words)
#define MT   3                    // M-tiles of 16 (rows 40..47 are zero pad)
#define KS   10                   // k-steps of 32 (K = 320)
#define FR   512                  // shorts per fragment slab [64 lanes][8]
#define SLABS (MT * KS)           // 30 A-slabs per block

typedef __attribute__((ext_vector_type(8))) short bf16x8;
typedef __attribute__((ext_vector_type(8))) short short8v;
typedef __attribute__((ext_vector_type(4))) float f32x4;
typedef __attribute__((ext_vector_type(4))) unsigned int uint4v;

// Fallback storage (only used if workspace too small). Preferred path: d_ws.
__device__ short g_Bpk[KS * 20 * FR];
__device__ short g_Wvpk[KS * 20 * FR];
__device__ float g_vlin[(size_t)BS_ * 320];

__device__ inline short f2bf(float f) {
    unsigned u = __float_as_uint(f);
    u += 0x7FFFu + ((u >> 16) & 1u);   // RNE
    return (short)(u >> 16);
}
__device__ inline float bf2f(short s) {
    return __uint_as_float(((unsigned)(unsigned short)s) << 16);
}

// round-half-up fp32->bf16 pack of 8 floats -> 16B fragment store
__device__ inline void pack_store(short* Am, int s, int lane, float4 fa, float4 fb) {
    unsigned u0 = __float_as_uint(fa.x) + 0x8000u;
    unsigned u1 = __float_as_uint(fa.y) + 0x8000u;
    unsigned u2 = __float_as_uint(fa.z) + 0x8000u;
    unsigned u3 = __float_as_uint(fa.w) + 0x8000u;
    unsigned u4 = __float_as_uint(fb.x) + 0x8000u;
    unsigned u5 = __float_as_uint(fb.y) + 0x8000u;
    unsigned u6 = __float_as_uint(fb.z) + 0x8000u;
    unsigned u7 = __float_as_uint(fb.w) + 0x8000u;
    uint4v w;
    w.x = __builtin_amdgcn_perm(u1, u0, 0x07060302u);
    w.y = __builtin_amdgcn_perm(u3, u2, 0x07060302u);
    w.z = __builtin_amdgcn_perm(u5, u4, 0x07060302u);
    w.w = __builtin_amdgcn_perm(u7, u6, 0x07060302u);
    *(uint4v*)(Am + ((size_t)s * 64 + lane) * 8) = w;
}

#define GB (KS * 20 * 64)         // 12,800 W fragment-groups per matrix
#define GT2 (GB + GB)             // 25,600 total -> 100 blocks

// Packs only the two weight matrices (Ws -> Bpk, Wv+bias -> Wvpk).
__global__ __launch_bounds__(256) void prep_small(
    const float* __restrict__ W, const float* __restrict__ bias,
    short* Bpk, short* Wvpk)
{
    if (!Bpk) { Bpk = g_Bpk; Wvpk = g_Wvpk; }
    const int id = blockIdx.x * 256 + threadIdx.x;
    if (id >= GT2) return;
    short8v o8 = {0, 0, 0, 0, 0, 0, 0, 0};
    if (id < GB) {
        const int lane = id & 63, g = id >> 6;
        const int q = lane >> 4, l15 = lane & 15;
        const int ks = g / 20, tile = g % 20;
        const int o = tile * 16 + l15, k0 = ks * 32 + q * 8;
        if (o < OUT_) {
            #pragma unroll
            for (int e = 0; e < 8; ++e) {
                const int k = k0 + e;
                if (k < D1_) o8[e] = f2bf(W[(size_t)o * (D1_ + D2_) + k]);
            }
        }
        *(short8v*)(Bpk + (size_t)id * 8) = o8;
    } else {
        const int id4 = id - GB;
        const int lane = id4 & 63, g = id4 >> 6;
        const int q = lane >> 4, l15 = lane & 15;
        const int ks = g / 20, tile = g % 20;
        const int o = tile * 16 + l15, k0 = ks * 32 + q * 8;
        if (o < OUT_) {
            #pragma unroll
            for (int e = 0; e < 8; ++e) {
                const int k = k0 + e;
                if (k < D2_)        o8[e] = f2bf(W[(size_t)o * (D1_ + D2_) + D1_ + k]);
                else if (k == 319)  o8[e] = f2bf(bias[o]);
            }
        }
        *(short8v*)(Wvpk + (size_t)id4 * 8) = o8;
    }
}

// vlin[row][col] = vec . Wv + bias   (4096 x 320, K=320)
// Reads vec fp32 directly (coalesced float4 + inline bf16 convert) — the old
// Vpk packing stage is gone. Same MFMA order/rounding as the passing r2 path.
__global__ __launch_bounds__(256) void vlin_direct(
    const float* __restrict__ vec, const short* Wvpk, float* vlin)
{
    if (!Wvpk) { Wvpk = g_Wvpk; vlin = g_vlin; }
    const int mtile = blockIdx.x;           // 0..255
    const int tid  = threadIdx.x;
    const int lane = tid & 63;
    const int wv   = tid >> 6;              // j-tile group 0..3
    const int q = lane >> 4, l15 = lane & 15;

    // A-fragments for rows mtile*16+l15: issue all loads, then convert.
    const float* vp = vec + (size_t)(mtile * 16 + l15) * D2_;
    float4 ra[KS], rb[KS];
    #pragma unroll
    for (int ks = 0; ks < KS; ++ks) {
        const int k0 = ks * 32 + q * 8;
        float4 fa = {0.f, 0.f, 0.f, 0.f}, fb = {0.f, 0.f, 0.f, 0.f};
        if (k0 < 296) { fa = *(const float4*)(vp + k0); fb = *(const float4*)(vp + k0 + 4); }
        else if (k0 == 296) { fa = *(const float4*)(vp + k0); }
        ra[ks] = fa; rb[ks] = fb;
    }
    bf16x8 frag[KS];
    #pragma unroll
    for (int ks = 0; ks < KS; ++ks) {
        const int k0 = ks * 32 + q * 8;
        const float f[8] = {ra[ks].x, ra[ks].y, ra[ks].z, ra[ks].w,
                            rb[ks].x, rb[ks].y, rb[ks].z, rb[ks].w};
        short8v av = {0, 0, 0, 0, 0, 0, 0, 0};
        #pragma unroll
        for (int e = 0; e < 8; ++e) {
            const int k = k0 + e;
            if (k < D2_)       av[e] = f2bf(f[e]);
            else if (k == 319) av[e] = (short)0x3F80;   // 1.0 (bias column)
        }
        frag[ks] = (bf16x8)av;
    }

    f32x4 acc[5];
    #pragma unroll
    for (int j = 0; j < 5; ++j) acc[j] = {0.f, 0.f, 0.f, 0.f};
    const short* pwb = Wvpk + (size_t)(wv * 5) * FR + lane * 8;
    #pragma unroll
    for (int ks = 0; ks < KS; ++ks) {
        #pragma unroll
        for (int j = 0; j < 5; ++j) {
            const bf16x8 b = *(const bf16x8*)(pwb + j * FR);
            acc[j] = __builtin_amdgcn_mfma_f32_16x16x32_bf16(frag[ks], b, acc[j], 0, 0, 0);
        }
        pwb += 20 * FR;
    }
    const int row0 = mtile * 16 + q * 4;
    #pragma unroll
    for (int j = 0; j < 5; ++j)
        #pragma unroll
        for (int r = 0; r < 4; ++r)
            vlin[(size_t)(row0 + r) * 320 + (wv * 5 + j) * 16 + l15] = acc[j][r];
}

// PPB=2: LDS 31.5 KB/block -> 5 blocks/CU resident (vs 2-3 at 53 KB).
// (256,2) is the proven spill-free regalloc regime; residency is set by
// LDS/VGPR, not by the launch-bounds hint.
__global__ __launch_bounds__(256, 2) void attn_fused(
    const float* __restrict__ seq,   // fp32 [4096,20,300]
    const int*   __restrict__ masks,
    const float* __restrict__ vvec,
    const short* Bpk,
    const float* vlinbuf,
    float*       __restrict__ out)
{
    if (!Bpk) { Bpk = g_Bpk; vlinbuf = g_vlin; }

    __shared__ short Am[MT * KS * FR];    // 30,720 B — bf16 A fragments
    __shared__ float sp[4][BM];           // 640 B
    __shared__ float alpha_lds[BM];       // 160 B  — total 31,520 B

    const int tid  = threadIdx.x;
    const int lane = tid & 63;
    const int wv   = tid >> 6;            // 0..3
    const int q    = lane >> 4;
    const int l15  = lane & 15;
    const int blk  = blockIdx.x;

    // ---- Phase 1: fp32 seq tile -> bf16 fragment slabs in LDS ----
    // 30 slabs / 4 waves = 8 rounds, fully unrolled load-all-then-pack.
    // Rows 40..47 (tile 2, l15>=8) are zeroed.
    {
        const float* sbase = seq + (size_t)blk * BM * D1_;
        float4 ra[8], rb[8];
        #pragma unroll
        for (int it = 0; it < 8; ++it) {
            const int s = wv + it * 4;
            float4 fa = {0.f, 0.f, 0.f, 0.f}, fb = {0.f, 0.f, 0.f, 0.f};
            if (s < SLABS) {
                const int tile = s / KS, ks = s % KS;
                const int row = tile * 16 + l15;
                const int k0 = ks * 32 + q * 8;
                if (row < BM) {
                    const float* p = sbase + (size_t)row * D1_ + k0;
                    if (k0 < 296) { fa = *(const float4*)p; fb = *(const float4*)(p + 4); }
                    else if (k0 == 296) { fa = *(const float4*)p; }
                }
            }
            ra[it] = fa; rb[it] = fb;
        }
        #pragma unroll
        for (int it = 0; it < 8; ++it) {
            const int s = wv + it * 4;
            if (s < SLABS) pack_store(Am, s, lane, ra[it], rb[it]);
        }
    }

    // v-vector + vlin register preloads before the barrier (latency hidden).
    float vj[5];
    #pragma unroll
    for (int j = 0; j < 5; ++j) {
        const int col = wv * 80 + j * 16 + l15;
        vj[j] = (col < OUT_) ? vvec[col] : 0.f;
    }
    float vlp[PPB][5];
    #pragma unroll
    for (int p = 0; p < PPB; ++p)
        #pragma unroll
        for (int j = 0; j < 5; ++j)
            vlp[p][j] = vlinbuf[(size_t)(blk * PPB + p) * 320 + wv * 80 + j * 16 + l15];
    __syncthreads();

    // ---- Phase 2: barrier-free GEMM. A from LDS, B from L2 (frag-packed) ----
    f32x4 acc[MT][5];
    #pragma unroll
    for (int i = 0; i < MT; ++i)
        #pragma unroll
        for (int j = 0; j < 5; ++j) acc[i][j] = {0.f, 0.f, 0.f, 0.f};

    const short* pb[5];
    #pragma unroll
    for (int j = 0; j < 5; ++j)
        pb[j] = Bpk + (size_t)(wv * 5 + j) * FR + lane * 8;

    #pragma unroll
    for (int ks = 0; ks < KS; ++ks) {
        bf16x8 a[MT], b[5];
        #pragma unroll
        for (int i = 0; i < MT; ++i)
            a[i] = *(const bf16x8*)(Am + (((size_t)i * KS + ks) * 64 + lane) * 8);
        #pragma unroll
        for (int j = 0; j < 5; ++j)
            b[j] = *(const bf16x8*)(pb[j] + (size_t)ks * 20 * FR);
        #pragma unroll
        for (int i = 0; i < MT; ++i)
            #pragma unroll
            for (int j = 0; j < 5; ++j)
                acc[i][j] = __builtin_amdgcn_mfma_f32_16x16x32_bf16(a[i], b[j], acc[i][j], 0, 0, 0);
    }

    // ---- epilogue: lin = acc + vlin; score[r] = sum_o tanh(lin) * v[o] ----
    // i=0: rows 0-15 (pair 0); i=1: rows 16-31 (boundary at 20); i=2: rows
    // 32-47 (pair 1; rows >=40 are pad, skipped at the sp write).
    #pragma unroll
    for (int i = 0; i < MT; ++i) {
        #pragma unroll
        for (int r = 0; r < 4; ++r) {
            const int row = i * 16 + q * 4 + r;
            const bool hi = (row >= 20);
            float s = 0.f;
            #pragma unroll
            for (int j = 0; j < 5; ++j) {
                const float vlv = (i == 0) ? vlp[0][j]
                                : (i == 2) ? vlp[1][j]
                                : (hi ? vlp[1][j] : vlp[0][j]);
                const float x = acc[i][j][r] + vlv;
                const float e = __expf(2.f * x);       // tanh(x) = 1 - 2/(e^{2x}+1)
                s += (1.f - 2.f / (e + 1.f)) * vj[j];
            }
            s += __shfl_xor(s, 1, 64);
            s += __shfl_xor(s, 2, 64);
            s += __shfl_xor(s, 4, 64);
            s += __shfl_xor(s, 8, 64);                 // sum 16 cols of tile
            if (l15 == 0 && row < BM) sp[wv][row] = s;
        }
    }
    __syncthreads();

    // ---- wave-parallel masked softmax: 32 lanes per pair ----
    if (tid < PPB * 32) {
        const int p = tid >> 5;            // pair 0..PPB-1
        const int w = tid & 31;            // 0..31, active w<20
        float s;
        if (w < WL_) {
            const int row = p * WL_ + w;
            const float sc = sp[0][row] + sp[1][row] + sp[2][row] + sp[3][row];
            const int mk = masks[(size_t)(blk * PPB + p) * WL_ + w];
            s = (mk == 0) ? NEG_INF : sc;
        } else {
            s = -INFINITY;                 // padding lanes: exp(-inf)=0
        }
        float m = s;
        #pragma unroll
        for (int off = 16; off; off >>= 1)
            m = fmaxf(m, __shfl_xor(m, off, 32));
        const float e = __expf(s - m);
        float sum = e;
        #pragma unroll
        for (int off = 16; off; off >>= 1)
            sum += __shfl_xor(sum, off, 32);
        if (w < WL_) alpha_lds[p * WL_ + w] = e / sum;
    }
    __syncthreads();

    // ---- weighted sum from the bf16 LDS fragments (staggered w start) ----
    if (tid < PPB * 38) {
        const int p = tid / 38, ch = tid % 38;
        const int ks2 = ch >> 2, q2 = ch & 3;
        const int wst = ch % WL_;
        float o8[8] = {0.f, 0.f, 0.f, 0.f, 0.f, 0.f, 0.f, 0.f};
        #pragma unroll
        for (int wi = 0; wi < WL_; ++wi) {
            int w = wst + wi; if (w >= WL_) w -= WL_;
            const int row = p * WL_ + w;
            const int tl = row >> 4, l = row & 15;
            const bf16x8 s8 = *(const bf16x8*)(Am + (((size_t)tl * KS + ks2) * 64 + q2 * 16 + l) * 8);
            const float a = alpha_lds[row];
            #pragma unroll
            for (int e2 = 0; e2 < 8; ++e2) o8[e2] += a * bf2f(s8[e2]);
        }
        const int d0 = ch * 8, gp = blk * PPB + p;
        float* dst = out + (size_t)gp * OUT_ + d0;
        if (d0 + 8 <= OUT_) {
            *(float4*)dst       = {o8[0], o8[1], o8[2], o8[3]};
            *(float4*)(dst + 4) = {o8[4], o8[5], o8[6], o8[7]};
        } else {                                   // d0 == 296: last 4 only
            *(float4*)dst = {o8[0], o8[1], o8[2], o8[3]};
        }
    }
}

extern "C" void kernel_launch(void* const* d_in, const int* in_sizes, int n_in,
                              void* d_out, int out_size, void* d_ws, size_t ws_size,
                              hipStream_t stream) {
    const float* seq   = (const float*)d_in[0];
    const float* vec   = (const float*)d_in[1];
    const int*   masks = (const int*)d_in[2];
    const float* W     = (const float*)d_in[3];
    const float* b     = (const float*)d_in[4];
    const float* v     = (const float*)d_in[5];
    float* out = (float*)d_out;

    constexpr size_t SZ_B = sizeof(short) * (size_t)KS * 20 * FR;   // 204,800
    constexpr size_t SZ_L = sizeof(float) * (size_t)BS_ * 320;      // 5,242,880
    constexpr size_t NEED = SZ_B * 2 + SZ_L;                        // 5,652,480
    short *Bpk = nullptr, *Wvpk = nullptr;
    float *vlin = nullptr;
    if (d_ws && ws_size >= NEED) {
        char* p = (char*)d_ws;
        Bpk  = (short*)p; p += SZ_B;
        Wvpk = (short*)p; p += SZ_B;
        vlin = (float*)p;
    }

    prep_small<<<(GT2 + 255) / 256, 256, 0, stream>>>(W, b, Bpk, Wvpk);
    vlin_direct<<<256, 256, 0, stream>>>(vec, Wvpk, vlin);
    attn_fused<<<NBLK, 256, 0, stream>>>(seq, masks, v, Bpk, vlin, out);
}